// Round 10
// baseline (130.517 us; speedup 1.0000x reference)
//
#include <hip/hip_runtime.h>

// ContrastiveLoss on MI355X (gfx950), B=8192, D=128, labels in [0,2048).
// loss = -(1/cnt) sum_{i: P_i>0} [ S_i/P_i - M - ln Z_i ]
//   Z_i = sum_{j != i} exp(sim_ij - M),  sim = E E^T / T,  M = 1/T (valid shift).
//   S_i = (e_i . g_{lab_i} - e_i . e_i) / T  with fp32 class sums g_c.
//   P_i = count[lab_i] - 1.
// R10: main fixed on two measured defects from R9:
//  (a) bank conflicts (540k): col stride 256 B ≡ 0 mod 32 banks, old swizzle
//      was useless. New layout: chunk (col,c) at 16B-unit
//      (col>>4)*256 + c*16 + ((col&15)^c)  -> reads AND writes 2-way max (free).
//  (b) occupancy (VGPR=176 -> 8%): 32-row waves + launch_bounds(256,4)
//      pins VGPR<=128, 4 blocks/CU.

#define BATCH 8192
#define DIMK  128
#define INV_T 14.285714285714286f
#define MSUB  14.285714285714286f
#define K1    20.609929155311264f   // INV_T * log2(e)
#define K2    20.609929155311264f   // MSUB  * log2(e)

typedef short bf16x8 __attribute__((ext_vector_type(8)));
typedef float f32x4  __attribute__((ext_vector_type(4)));

__device__ __forceinline__ unsigned short f2bf_rne(float f) {
    unsigned u = __float_as_uint(f);
    u += 0x7FFFu + ((u >> 16) & 1u);
    return (unsigned short)(u >> 16);
}
__device__ __forceinline__ float bf2f(unsigned short b) {
    return __uint_as_float(((unsigned)b) << 16);
}

// ---------------------------------------------------------------------------
// Prep: blocks [0,1024): fp32->bf16 cvt (4 elems/thread) + zero the Z-partial
//       region (zpartR 1 MB + zcol 32 KB = 67584 float4s).
//       blocks [1024,1536): class sums, 1 class per wave, labels staged in LDS.
__global__ __launch_bounds__(256) void
prep_kernel(const float* __restrict__ emb, const int* __restrict__ labels,
            ushort* __restrict__ Ebf, float* __restrict__ gsum, int* __restrict__ gcnt,
            float4* __restrict__ zzero) {
    if (blockIdx.x < 1024) {
        int i = blockIdx.x * 256 + threadIdx.x;
        if (i < 67584) {
            float4 z = {0.f, 0.f, 0.f, 0.f};
            zzero[i] = z;
        }
        float4 v = ((const float4*)emb)[i];
        ushort4 o;
        o.x = f2bf_rne(v.x); o.y = f2bf_rne(v.y);
        o.z = f2bf_rne(v.z); o.w = f2bf_rne(v.w);
        ((ushort4*)Ebf)[i] = o;
    } else {
        __shared__ int labs[BATCH];           // 32 KB
        const int tid = threadIdx.x;
#pragma unroll
        for (int it = 0; it < 8; ++it)
            ((int4*)labs)[it * 256 + tid] = ((const int4*)labels)[it * 256 + tid];
        __syncthreads();

        const int lane = tid & 63;
        const int wid  = tid >> 6;
        const int c    = (blockIdx.x - 1024) * 4 + wid;   // class id [0,2048)
        float2 acc = {0.f, 0.f};
        int cnt = 0;
        int nl = labs[lane];
        for (int j0 = 0; j0 < BATCH; j0 += 64) {
            int cur = nl;
            int nidx = j0 + 64 < BATCH ? j0 + 64 : 0;
            nl = labs[nidx + lane];
            unsigned long long m = __ballot(cur == c);
            cnt += __popcll(m);
            while (m) {
                int j = __ffsll(m) - 1;
                m &= m - 1;
                float2 v = *(const float2*)(emb + (size_t)(j0 + j) * DIMK + lane * 2);
                acc.x += v.x; acc.y += v.y;
            }
        }
        *(float2*)(gsum + (size_t)c * DIMK + lane * 2) = acc;
        if (lane == 0) gcnt[c] = cnt;
    }
}

// ---------------------------------------------------------------------------
// Main: Z partials over the upper triangle. Grid 1056 = 528 macro-tiles x 2
// row-halves, block 256 (4 waves). Macro-tile (ti,tj), tj>=ti; this block
// covers rows [ti*256 + half*128, +128) x cols [tj*256, +256).
// Cols staged in two 128-col LDS phases, conflict-free XOR layout:
//   chunk (col, c) -> 16B-unit (col>>4)*256 + c*16 + ((col&15)^c).
// Wave owns 32 rows (afrag[2][4]=32 VGPRs); launch_bounds(256,4) pins
// VGPR<=128 -> 4 blocks/CU. Row partials -> zpartR[tj][row] (plain stores).
// Col partials (off-diag only) -> cpart LDS combine -> atomicAdd zcol[col].
__global__ __launch_bounds__(256, 4) void
contrastive_main(const ushort* __restrict__ Ebf, float* __restrict__ zpartR,
                 float* __restrict__ zcol) {
    __shared__ __align__(16) ushort Bs[2048 * 8];     // 32 KB (2048 16B units)
    __shared__ float cpart[4][256];                   // 4 KB
    const int tid  = threadIdx.x;
    const int lane = tid & 63;
    const int wid  = tid >> 6;
    const int quad = lane >> 4;
    const int l16  = lane & 15;

    // block -> (ti, tj, half)
    int b = blockIdx.x >> 1;
    const int half = blockIdx.x & 1;
    int ti = 0;
    while (b >= 32 - ti) { b -= 32 - ti; ++ti; }
    const int tj = ti + b;
    const int row_base = ti * 256 + half * 128 + wid * 32;

    // A-fragments for this wave's 32 rows (register-resident), from global/L2.
    bf16x8 afrag[2][4];
#pragma unroll
    for (int mt = 0; mt < 2; ++mt)
#pragma unroll
        for (int kk = 0; kk < 4; ++kk)
            afrag[mt][kk] = *(const bf16x8*)(Ebf + (size_t)(row_base + mt * 16 + l16) * DIMK
                                             + kk * 32 + quad * 8);

    float zacc[8];
#pragma unroll
    for (int s = 0; s < 8; ++s) zacc[s] = 0.f;

#pragma unroll
    for (int phase = 0; phase < 2; ++phase) {
        const int col_base = tj * 256 + phase * 128;
        __syncthreads();   // Bs safe to overwrite (cheap no-op on phase 0)
        // Stage 128 cols: 2048 16B chunks; thread t handles chunk f = it*256+t:
        // col = f>>4, c = f&15; global read coalesced (16 lanes = 256B of one col);
        // LDS write at swizzled unit (col>>4)*256 + c*16 + ((col&15)^c) -> 2-way.
#pragma unroll
        for (int it = 0; it < 8; ++it) {
            int f   = it * 256 + tid;
            int col = f >> 4;
            int c   = f & 15;
            uint4 v = *(const uint4*)(Ebf + (size_t)(col_base + col) * DIMK + c * 8);
            *(uint4*)&Bs[((col >> 4) * 256 + c * 16 + ((col & 15) ^ c)) * 8] = v;
        }
        __syncthreads();

        for (int nt = 0; nt < 8; ++nt) {
            bf16x8 bfrag[4];
#pragma unroll
            for (int kk = 0; kk < 4; ++kk) {
                const int c2 = kk * 4 + quad;
                bfrag[kk] = *(const bf16x8*)&Bs[(nt * 256 + c2 * 16 + (l16 ^ c2)) * 8];
            }

            float csum = 0.f;
#pragma unroll
            for (int mt = 0; mt < 2; ++mt) {
                f32x4 c = {0.f, 0.f, 0.f, 0.f};
#pragma unroll
                for (int kk = 0; kk < 4; ++kk)
                    c = __builtin_amdgcn_mfma_f32_16x16x32_bf16(afrag[mt][kk], bfrag[kk], c, 0, 0, 0);
#pragma unroll
                for (int r = 0; r < 4; ++r) {
                    float e = __builtin_amdgcn_exp2f(__builtin_fmaf(c[r], K1, -K2));
                    zacc[mt * 4 + r] += e;
                    csum += e;
                }
            }
            // col partial for col (phase*128 + nt*16 + l16) over this wave's 32 rows
            csum += __shfl_xor(csum, 16, 64);
            csum += __shfl_xor(csum, 32, 64);
            if (quad == 0) cpart[wid][phase * 128 + nt * 16 + l16] = csum;
        }
    }

    // Row partials: reduce each row-slot over the 16 lanes sharing the row.
#pragma unroll
    for (int s = 0; s < 8; ++s) {
        float z = zacc[s];
#pragma unroll
        for (int m = 1; m <= 8; m <<= 1) z += __shfl_xor(z, m, 64);
        if (l16 == 0) {
            int row = row_base + (s >> 2) * 16 + quad * 4 + (s & 3);
            zpartR[(size_t)tj * BATCH + row] = z;
        }
    }

    // Col partials: combine the 4 waves, one distributed atomic per column.
    __syncthreads();
    if (ti != tj) {
        float s = cpart[0][tid] + cpart[1][tid] + cpart[2][tid] + cpart[3][tid];
        atomicAdd(&zcol[tj * 256 + tid], s);
    }
}

// ---------------------------------------------------------------------------
// Finalize 1: 512 blocks x 256 (4 waves); each wave processes 4 rows.
// Per row: lane l covers dims 2l,2l+1; lanes 0..31 read zpartR, lane 32 zcol.
__global__ __launch_bounds__(256) void
finalize1(const float* __restrict__ emb, const ushort* __restrict__ Ebf,
          const int* __restrict__ labels, const float* __restrict__ gsum,
          const int* __restrict__ gcnt, const float* __restrict__ zpartR,
          const float* __restrict__ zcol,
          float* __restrict__ bpart, int* __restrict__ bcnt) {
    __shared__ float sf[4];
    __shared__ int   si[4];
    const int lane = threadIdx.x & 63;
    const int wid  = threadIdx.x >> 6;

    float wsum = 0.f;
    int   wcnt = 0;
#pragma unroll
    for (int it = 0; it < 4; ++it) {
        const int r   = blockIdx.x * 16 + wid * 4 + it;
        const int lab = labels[r];
        const int P   = gcnt[lab] - 1;

        float2 ev = *(const float2*)(emb  + (size_t)r   * DIMK + lane * 2);
        float2 gv = *(const float2*)(gsum + (size_t)lab * DIMK + lane * 2);
        unsigned bb = *(const unsigned*)(Ebf + (size_t)r * DIMK + lane * 2);
        float b0 = bf2f((unsigned short)(bb & 0xFFFF));
        float b1 = bf2f((unsigned short)(bb >> 16));

        float dotg = ev.x * gv.x + ev.y * gv.y;
        float ssd  = ev.x * ev.x + ev.y * ev.y;
        float sdbf = b0 * b0 + b1 * b1;
        float Z = 0.f;
        if (lane < 32)       Z = zpartR[(size_t)lane * BATCH + r];
        else if (lane == 32) Z = zcol[r];

#pragma unroll
        for (int m = 1; m <= 32; m <<= 1) {
            dotg += __shfl_xor(dotg, m, 64);
            ssd  += __shfl_xor(ssd,  m, 64);
            sdbf += __shfl_xor(sdbf, m, 64);
            Z    += __shfl_xor(Z,    m, 64);
        }
        Z -= __builtin_amdgcn_exp2f(__builtin_fmaf(sdbf, K1, -K2));  // remove diagonal

        const bool has = (P > 0);
        wsum += has ? ((dotg - ssd) * INV_T / (float)P - MSUB - __logf(Z)) : 0.f;
        wcnt += has ? 1 : 0;
    }

    if (lane == 0) { sf[wid] = wsum; si[wid] = wcnt; }
    __syncthreads();
    if (threadIdx.x == 0) {
        bpart[blockIdx.x] = sf[0] + sf[1] + sf[2] + sf[3];
        bcnt [blockIdx.x] = si[0] + si[1] + si[2] + si[3];
    }
}

// ---------------------------------------------------------------------------
// Finalize 2: reduce 512 block partials -> scalar loss. 1 block x 256.
__global__ __launch_bounds__(256) void
finalize2(const float* __restrict__ bpart, const int* __restrict__ bcnt,
          float* __restrict__ out) {
    __shared__ float sf[4];
    __shared__ int   si[4];
    const int t = threadIdx.x;
    float v = 0.f; int c = 0;
#pragma unroll
    for (int k = 0; k < 2; ++k) {
        v += bpart[t + k * 256];
        c += bcnt [t + k * 256];
    }
#pragma unroll
    for (int m = 1; m <= 32; m <<= 1) {
        v += __shfl_xor(v, m, 64);
        c += __shfl_xor(c, m, 64);
    }
    if ((t & 63) == 0) { sf[t >> 6] = v; si[t >> 6] = c; }
    __syncthreads();
    if (t == 0) {
        float tot = sf[0] + sf[1] + sf[2] + sf[3];
        int cc = si[0] + si[1] + si[2] + si[3];
        out[0] = -tot / (float)(cc > 0 ? cc : 1);
    }
}

extern "C" void kernel_launch(void* const* d_in, const int* in_sizes, int n_in,
                              void* d_out, int out_size, void* d_ws, size_t ws_size,
                              hipStream_t stream) {
    const float* emb  = (const float*)d_in[0];
    const int* labels = (const int*)d_in[1];
    float* out        = (float*)d_out;

    char* ws = (char*)d_ws;
    ushort* Ebf    = (ushort*)ws;                         // 2 MB  (8192*128*2)
    float*  zpartR = (float*)(ws + (2u << 20));           // 1 MB  (32*8192*4)
    float*  zcol   = (float*)(ws + (3u << 20));           // 32 KB (8192*4)
    float*  gsum   = (float*)(ws + (4u << 20));           // 1 MB  (2048*128*4)
    int*    gcnt   = (int*)  (ws + (5u << 20));           // 8 KB
    float*  bpart  = (float*)(ws + (5u << 20) + 8192);    // 8 KB
    int*    bcnt   = (int*)  (ws + (5u << 20) + 16384);   // 8 KB

    prep_kernel<<<1536, 256, 0, stream>>>(emb, labels, Ebf, gsum, gcnt, (float4*)zpartR);
    contrastive_main<<<1056, 256, 0, stream>>>(Ebf, zpartR, zcol);
    finalize1<<<512, 256, 0, stream>>>(emb, Ebf, labels, gsum, gcnt, zpartR, zcol, bpart, bcnt);
    finalize2<<<1, 256, 0, stream>>>(bpart, bcnt, out);
}

// Round 11
// 101.381 us; speedup vs baseline: 1.2874x; 1.2874x over previous
//
#include <hip/hip_runtime.h>

// ContrastiveLoss on MI355X (gfx950), B=8192, D=128, labels in [0,2048).
// loss = -(1/cnt) sum_{i: P_i>0} [ S_i/P_i - M - ln Z_i ]
//   Z_i = sum_{j != i} exp(sim_ij - M),  sim = E E^T / T,  M = 1/T (valid shift).
//   S_i = (e_i . g_{lab_i} - e_i . e_i) / T  with fp32 class sums g_c.
//   P_i = count[lab_i] - 1.
// R11: R10's conflict-free swizzle (verified: SQ_LDS_BANK_CONFLICT=0) with
//      plain __launch_bounds__(256) on main. Lesson (R3/R7/R10, 3x measured):
//      explicit min-waves in launch_bounds on an MFMA kernel forces the
//      64/64 VGPR/AGPR split and spills once live-set > 64 arch regs.

#define BATCH 8192
#define DIMK  128
#define INV_T 14.285714285714286f
#define MSUB  14.285714285714286f
#define K1    20.609929155311264f   // INV_T * log2(e)
#define K2    20.609929155311264f   // MSUB  * log2(e)

typedef short bf16x8 __attribute__((ext_vector_type(8)));
typedef float f32x4  __attribute__((ext_vector_type(4)));

__device__ __forceinline__ unsigned short f2bf_rne(float f) {
    unsigned u = __float_as_uint(f);
    u += 0x7FFFu + ((u >> 16) & 1u);
    return (unsigned short)(u >> 16);
}
__device__ __forceinline__ float bf2f(unsigned short b) {
    return __uint_as_float(((unsigned)b) << 16);
}

// ---------------------------------------------------------------------------
// Prep: blocks [0,1024): fp32->bf16 cvt (4 elems/thread) + zero the Z-partial
//       region (zpartR 1 MB + zcol 32 KB = 67584 float4s).
//       blocks [1024,1536): class sums, 1 class per wave, labels staged in LDS.
__global__ __launch_bounds__(256) void
prep_kernel(const float* __restrict__ emb, const int* __restrict__ labels,
            ushort* __restrict__ Ebf, float* __restrict__ gsum, int* __restrict__ gcnt,
            float4* __restrict__ zzero) {
    if (blockIdx.x < 1024) {
        int i = blockIdx.x * 256 + threadIdx.x;
        if (i < 67584) {
            float4 z = {0.f, 0.f, 0.f, 0.f};
            zzero[i] = z;
        }
        float4 v = ((const float4*)emb)[i];
        ushort4 o;
        o.x = f2bf_rne(v.x); o.y = f2bf_rne(v.y);
        o.z = f2bf_rne(v.z); o.w = f2bf_rne(v.w);
        ((ushort4*)Ebf)[i] = o;
    } else {
        __shared__ int labs[BATCH];           // 32 KB
        const int tid = threadIdx.x;
#pragma unroll
        for (int it = 0; it < 8; ++it)
            ((int4*)labs)[it * 256 + tid] = ((const int4*)labels)[it * 256 + tid];
        __syncthreads();

        const int lane = tid & 63;
        const int wid  = tid >> 6;
        const int c    = (blockIdx.x - 1024) * 4 + wid;   // class id [0,2048)
        float2 acc = {0.f, 0.f};
        int cnt = 0;
        int nl = labs[lane];
        for (int j0 = 0; j0 < BATCH; j0 += 64) {
            int cur = nl;
            int nidx = j0 + 64 < BATCH ? j0 + 64 : 0;
            nl = labs[nidx + lane];
            unsigned long long m = __ballot(cur == c);
            cnt += __popcll(m);
            while (m) {
                int j = __ffsll(m) - 1;
                m &= m - 1;
                float2 v = *(const float2*)(emb + (size_t)(j0 + j) * DIMK + lane * 2);
                acc.x += v.x; acc.y += v.y;
            }
        }
        *(float2*)(gsum + (size_t)c * DIMK + lane * 2) = acc;
        if (lane == 0) gcnt[c] = cnt;
    }
}

// ---------------------------------------------------------------------------
// Main: Z partials over the upper triangle. Grid 1056 = 528 macro-tiles x 2
// row-halves, block 256 (4 waves). Macro-tile (ti,tj), tj>=ti; this block
// covers rows [ti*256 + half*128, +128) x cols [tj*256, +256).
// Cols staged in two 128-col LDS phases, conflict-free XOR layout
// (measured: SQ_LDS_BANK_CONFLICT = 0):
//   chunk (col, c) -> 16B-unit (col>>4)*256 + c*16 + ((col&15)^c).
// Wave owns 32 rows (afrag[2][4]=32 VGPRs). PLAIN launch_bounds(256):
// min-waves pinning causes the VGPR/AGPR split-spill (R3/R7/R10).
// Row partials -> zpartR[tj][row] (plain stores). Col partials (off-diag
// only) -> cpart LDS combine -> atomicAdd zcol[col] (~16 adds/address).
__global__ __launch_bounds__(256) void
contrastive_main(const ushort* __restrict__ Ebf, float* __restrict__ zpartR,
                 float* __restrict__ zcol) {
    __shared__ __align__(16) ushort Bs[2048 * 8];     // 32 KB (2048 16B units)
    __shared__ float cpart[4][256];                   // 4 KB
    const int tid  = threadIdx.x;
    const int lane = tid & 63;
    const int wid  = tid >> 6;
    const int quad = lane >> 4;
    const int l16  = lane & 15;

    // block -> (ti, tj, half)
    int b = blockIdx.x >> 1;
    const int half = blockIdx.x & 1;
    int ti = 0;
    while (b >= 32 - ti) { b -= 32 - ti; ++ti; }
    const int tj = ti + b;
    const int row_base = ti * 256 + half * 128 + wid * 32;

    // A-fragments for this wave's 32 rows (register-resident), from global/L2.
    bf16x8 afrag[2][4];
#pragma unroll
    for (int mt = 0; mt < 2; ++mt)
#pragma unroll
        for (int kk = 0; kk < 4; ++kk)
            afrag[mt][kk] = *(const bf16x8*)(Ebf + (size_t)(row_base + mt * 16 + l16) * DIMK
                                             + kk * 32 + quad * 8);

    float zacc[8];
#pragma unroll
    for (int s = 0; s < 8; ++s) zacc[s] = 0.f;

#pragma unroll
    for (int phase = 0; phase < 2; ++phase) {
        const int col_base = tj * 256 + phase * 128;
        __syncthreads();   // Bs safe to overwrite (cheap no-op on phase 0)
        // Stage 128 cols: 2048 16B chunks; thread t handles chunk f = it*256+t:
        // col = f>>4, c = f&15; global read coalesced (16 lanes = 256B of one col);
        // LDS write at swizzled unit (col>>4)*256 + c*16 + ((col&15)^c) -> 2-way.
#pragma unroll
        for (int it = 0; it < 8; ++it) {
            int f   = it * 256 + tid;
            int col = f >> 4;
            int c   = f & 15;
            uint4 v = *(const uint4*)(Ebf + (size_t)(col_base + col) * DIMK + c * 8);
            *(uint4*)&Bs[((col >> 4) * 256 + c * 16 + ((col & 15) ^ c)) * 8] = v;
        }
        __syncthreads();

        for (int nt = 0; nt < 8; ++nt) {
            bf16x8 bfrag[4];
#pragma unroll
            for (int kk = 0; kk < 4; ++kk) {
                const int c2 = kk * 4 + quad;
                bfrag[kk] = *(const bf16x8*)&Bs[(nt * 256 + c2 * 16 + (l16 ^ c2)) * 8];
            }

            float csum = 0.f;
#pragma unroll
            for (int mt = 0; mt < 2; ++mt) {
                f32x4 c = {0.f, 0.f, 0.f, 0.f};
#pragma unroll
                for (int kk = 0; kk < 4; ++kk)
                    c = __builtin_amdgcn_mfma_f32_16x16x32_bf16(afrag[mt][kk], bfrag[kk], c, 0, 0, 0);
#pragma unroll
                for (int r = 0; r < 4; ++r) {
                    float e = __builtin_amdgcn_exp2f(__builtin_fmaf(c[r], K1, -K2));
                    zacc[mt * 4 + r] += e;
                    csum += e;
                }
            }
            // col partial for col (phase*128 + nt*16 + l16) over this wave's 32 rows
            csum += __shfl_xor(csum, 16, 64);
            csum += __shfl_xor(csum, 32, 64);
            if (quad == 0) cpart[wid][phase * 128 + nt * 16 + l16] = csum;
        }
    }

    // Row partials: reduce each row-slot over the 16 lanes sharing the row.
#pragma unroll
    for (int s = 0; s < 8; ++s) {
        float z = zacc[s];
#pragma unroll
        for (int m = 1; m <= 8; m <<= 1) z += __shfl_xor(z, m, 64);
        if (l16 == 0) {
            int row = row_base + (s >> 2) * 16 + quad * 4 + (s & 3);
            zpartR[(size_t)tj * BATCH + row] = z;
        }
    }

    // Col partials: combine the 4 waves, one distributed atomic per column.
    __syncthreads();
    if (ti != tj) {
        float s = cpart[0][tid] + cpart[1][tid] + cpart[2][tid] + cpart[3][tid];
        atomicAdd(&zcol[tj * 256 + tid], s);
    }
}

// ---------------------------------------------------------------------------
// Finalize 1: 512 blocks x 256 (4 waves); each wave processes 4 rows.
// Per row: lane l covers dims 2l,2l+1; lanes 0..31 read zpartR, lane 32 zcol.
__global__ __launch_bounds__(256) void
finalize1(const float* __restrict__ emb, const ushort* __restrict__ Ebf,
          const int* __restrict__ labels, const float* __restrict__ gsum,
          const int* __restrict__ gcnt, const float* __restrict__ zpartR,
          const float* __restrict__ zcol,
          float* __restrict__ bpart, int* __restrict__ bcnt) {
    __shared__ float sf[4];
    __shared__ int   si[4];
    const int lane = threadIdx.x & 63;
    const int wid  = threadIdx.x >> 6;

    float wsum = 0.f;
    int   wcnt = 0;
#pragma unroll
    for (int it = 0; it < 4; ++it) {
        const int r   = blockIdx.x * 16 + wid * 4 + it;
        const int lab = labels[r];
        const int P   = gcnt[lab] - 1;

        float2 ev = *(const float2*)(emb  + (size_t)r   * DIMK + lane * 2);
        float2 gv = *(const float2*)(gsum + (size_t)lab * DIMK + lane * 2);
        unsigned bb = *(const unsigned*)(Ebf + (size_t)r * DIMK + lane * 2);
        float b0 = bf2f((unsigned short)(bb & 0xFFFF));
        float b1 = bf2f((unsigned short)(bb >> 16));

        float dotg = ev.x * gv.x + ev.y * gv.y;
        float ssd  = ev.x * ev.x + ev.y * ev.y;
        float sdbf = b0 * b0 + b1 * b1;
        float Z = 0.f;
        if (lane < 32)       Z = zpartR[(size_t)lane * BATCH + r];
        else if (lane == 32) Z = zcol[r];

#pragma unroll
        for (int m = 1; m <= 32; m <<= 1) {
            dotg += __shfl_xor(dotg, m, 64);
            ssd  += __shfl_xor(ssd,  m, 64);
            sdbf += __shfl_xor(sdbf, m, 64);
            Z    += __shfl_xor(Z,    m, 64);
        }
        Z -= __builtin_amdgcn_exp2f(__builtin_fmaf(sdbf, K1, -K2));  // remove diagonal

        const bool has = (P > 0);
        wsum += has ? ((dotg - ssd) * INV_T / (float)P - MSUB - __logf(Z)) : 0.f;
        wcnt += has ? 1 : 0;
    }

    if (lane == 0) { sf[wid] = wsum; si[wid] = wcnt; }
    __syncthreads();
    if (threadIdx.x == 0) {
        bpart[blockIdx.x] = sf[0] + sf[1] + sf[2] + sf[3];
        bcnt [blockIdx.x] = si[0] + si[1] + si[2] + si[3];
    }
}

// ---------------------------------------------------------------------------
// Finalize 2: reduce 512 block partials -> scalar loss. 1 block x 256.
__global__ __launch_bounds__(256) void
finalize2(const float* __restrict__ bpart, const int* __restrict__ bcnt,
          float* __restrict__ out) {
    __shared__ float sf[4];
    __shared__ int   si[4];
    const int t = threadIdx.x;
    float v = 0.f; int c = 0;
#pragma unroll
    for (int k = 0; k < 2; ++k) {
        v += bpart[t + k * 256];
        c += bcnt [t + k * 256];
    }
#pragma unroll
    for (int m = 1; m <= 32; m <<= 1) {
        v += __shfl_xor(v, m, 64);
        c += __shfl_xor(c, m, 64);
    }
    if ((t & 63) == 0) { sf[t >> 6] = v; si[t >> 6] = c; }
    __syncthreads();
    if (t == 0) {
        float tot = sf[0] + sf[1] + sf[2] + sf[3];
        int cc = si[0] + si[1] + si[2] + si[3];
        out[0] = -tot / (float)(cc > 0 ? cc : 1);
    }
}

extern "C" void kernel_launch(void* const* d_in, const int* in_sizes, int n_in,
                              void* d_out, int out_size, void* d_ws, size_t ws_size,
                              hipStream_t stream) {
    const float* emb  = (const float*)d_in[0];
    const int* labels = (const int*)d_in[1];
    float* out        = (float*)d_out;

    char* ws = (char*)d_ws;
    ushort* Ebf    = (ushort*)ws;                         // 2 MB  (8192*128*2)
    float*  zpartR = (float*)(ws + (2u << 20));           // 1 MB  (32*8192*4)
    float*  zcol   = (float*)(ws + (3u << 20));           // 32 KB (8192*4)
    float*  gsum   = (float*)(ws + (4u << 20));           // 1 MB  (2048*128*4)
    int*    gcnt   = (int*)  (ws + (5u << 20));           // 8 KB
    float*  bpart  = (float*)(ws + (5u << 20) + 8192);    // 8 KB
    int*    bcnt   = (int*)  (ws + (5u << 20) + 16384);   // 8 KB

    prep_kernel<<<1536, 256, 0, stream>>>(emb, labels, Ebf, gsum, gcnt, (float4*)zpartR);
    contrastive_main<<<1056, 256, 0, stream>>>(Ebf, zpartR, zcol);
    finalize1<<<512, 256, 0, stream>>>(emb, Ebf, labels, gsum, gcnt, zpartR, zcol, bpart, bcnt);
    finalize2<<<1, 256, 0, stream>>>(bpart, bcnt, out);
}